// Round 6
// baseline (197.688 us; speedup 1.0000x reference)
//
#include <hip/hip_runtime.h>
#include <hip/hip_bf16.h>

#define BB   2
#define NN   128
#define SS   4
#define DGG  8
#define CIN  4
#define COUT 8
#define HH   32
#define NT   512   // 8 waves/block; 4 blocks/CU -> 32 waves/CU

typedef __attribute__((ext_vector_type(4))) float          fvec4;
typedef __attribute__((ext_vector_type(4))) unsigned short usvec4;
typedef __attribute__((ext_vector_type(8))) unsigned short usvec8;
typedef __attribute__((ext_vector_type(2))) __fp16         half2v;
typedef __attribute__((ext_vector_type(8))) __fp16         f16x8;
typedef __attribute__((ext_vector_type(4))) float          f32x4;
typedef __attribute__((ext_vector_type(4))) unsigned int   uvec4;

__device__ __forceinline__ float bf2f(unsigned short u) {
    return __uint_as_float(((unsigned int)u) << 16);
}
__device__ __forceinline__ float silu_f(float x) {
    float e = __builtin_amdgcn_exp2f(x * -1.44269504f);
    return x * __builtin_amdgcn_rcpf(1.0f + e);
}
__device__ __forceinline__ float exp_f(float x) {
    return __builtin_amdgcn_exp2f(x * 1.44269504f);
}

__device__ __forceinline__ unsigned int pk2u(float a, float b) {
#if __has_builtin(__builtin_amdgcn_cvt_pkrtz)
    half2v h = __builtin_amdgcn_cvt_pkrtz(a, b);
#else
    half2v h; h[0] = (__fp16)a; h[1] = (__fp16)b;
#endif
    union { half2v h; unsigned int u; } x; x.h = h; return x.u;
}
union FU { uvec4 u; f16x8 h; };
__device__ __forceinline__ f16x8 mk_frag(unsigned a, unsigned b, unsigned c, unsigned d) {
    FU x; x.u = (uvec4){a, b, c, d}; return x.h;
}
__device__ __forceinline__ f16x8 mk_fragv(uvec4 u) {
    FU x; x.u = u; return x.h;
}
// volatile LDS fragment loads — volatile is the POINT: it stops the compiler
// hoisting loop-invariant fragment reads into resident registers (that
// hoisting is what pinned the R3 body at ~128 unified regs and killed both
// TLP (R4 spill) and ILP (R5 spill)).
__device__ __forceinline__ uvec4 vldu(const unsigned* p) {
    return *(volatile const uvec4*)p;
}
__device__ __forceinline__ fvec4 vldf(const float* p) {
    return *(volatile const fvec4*)p;
}
// silu + pack two f32x4 MFMA outputs into one B-fragment (j = 0..7)
__device__ __forceinline__ f16x8 silu_frag(f32x4 a, f32x4 b) {
    return mk_frag(pk2u(silu_f(a[0]), silu_f(a[1])),
                   pk2u(silu_f(a[2]), silu_f(a[3])),
                   pk2u(silu_f(b[0]), silu_f(b[1])),
                   pk2u(silu_f(b[2]), silu_f(b[3])));
}

__device__ __forceinline__ float loadS(const void* p, int idx, int fmode) {
    return fmode ? bf2f(((const unsigned short*)p)[idx])
                 : ((const float*)p)[idx];
}
__device__ __forceinline__ void load8(const void* p, int base, int fmode, float* dst) {
    if (fmode) {
        usvec8 v = *(const usvec8*)((const unsigned short*)p + base);
#pragma unroll
        for (int d = 0; d < 8; ++d) dst[d] = bf2f(v[d]);
    } else {
        fvec4 a = *(const fvec4*)((const float*)p + base);
        fvec4 b = *(const fvec4*)((const float*)p + base + 4);
        dst[0] = a[0]; dst[1] = a[1]; dst[2] = a[2]; dst[3] = a[3];
        dst[4] = b[0]; dst[5] = b[1]; dst[6] = b[2]; dst[7] = b[3];
    }
}
__device__ __forceinline__ int load_mask(const void* p, int idx, int mmode) {
    if (mmode == 0) return ((const int*)p)[idx] != 0;
    if (mmode == 1) return ((const unsigned short*)p)[idx] != 0;
    if (mmode == 2) return ((const unsigned char*)p)[idx] != 0;
    return ((const unsigned int*)p)[idx] != 0;
}
__device__ __forceinline__ void stage_pk(unsigned int* dst, const void* src,
                                         int pairs, int fmode, int tid) {
    if (fmode) {
        const unsigned short* s = (const unsigned short*)src;
        for (int x = tid; x < pairs; x += NT)
            dst[x] = pk2u(bf2f(s[2 * x]), bf2f(s[2 * x + 1]));
    } else {
        const float* s = (const float*)src;
        for (int x = tid; x < pairs; x += NT)
            dst[x] = pk2u(s[2 * x], s[2 * x + 1]);
    }
}
__device__ __forceinline__ void copy_arr(float* sm, const void* src, int off,
                                         int cnt, int fmode, int tid) {
    if (fmode) {
        const unsigned short* s = (const unsigned short*)src;
        for (int x = tid; x < cnt; x += NT) sm[off + x] = bf2f(s[x]);
    } else {
        const float* s = (const float*)src;
        for (int x = tid; x < cnt; x += NT) sm[off + x] = s[x];
    }
}
// modes: [0]=float dtype (0=f32,1=bf16), [1]=mask dtype (0=i32,1=bf16,2=u8,3=f32)
__device__ __forceinline__ void detect_inline(const void* g_mask, const void* g_coset,
                                              int tid, int* smi, int slot) {
    if (tid < 64) {
        const unsigned short* cu = (const unsigned short*)g_coset;
        unsigned short v = cu[2 * tid];
        int e = (v >> 7) & 0xFF;
        int hits = __popcll(__ballot(e >= 110 && e <= 135));
        int fmode_ = (hits > 32) ? 1 : 0;
        const unsigned short* mu = (const unsigned short*)g_mask;
        int evenBF = 0, any3 = 0, anyByte = 0;
        for (int r = 0; r < 8; ++r) {
            int idx = tid + r * 64;
            unsigned short m = mu[idx];
            if (m == 0x3F80) { any3 = 1; if (!(idx & 1)) evenBF = 1; }
            if (m == 0x0101 || m == 0x0100) anyByte = 1;
        }
        evenBF  = (__ballot(evenBF)  != 0ull);
        any3    = (__ballot(any3)    != 0ull);
        anyByte = (__ballot(anyByte) != 0ull);
        if (tid == 0) {
            smi[slot]     = fmode_;
            smi[slot + 1] = evenBF ? 1 : (any3 ? 3 : (anyByte ? 2 : 0));
        }
    }
}

// LDS layout (u32 units).  All weights live HERE, not in registers; the body
// streams them per iteration (volatile b128 reads, broadcast within a quad).
// Biases: b1y folded into A at k2 (B supplies constant 1.0 at k2); b1g folded
// at k8 via quad-1 A rows from U_GB1q (B quad-1 reads the constant region
// U_CB1 = {pk(1,0),0,0,0, 0,0,0,0}; quads 2-3 read the zero half).  b2 via
// MFMA C operand read from LDS.  b3 added post-MFMA in f32.
#define UG_G    0      // 2048: pairwise_g slice, packed f16 [pos][4]
#define F_FA    2048   // 2048 f32: coset b-slice [pos][ci]
#define U_YW1n  4096   // 512: [ci][32 rows][4]: (w0,w1),(b1y,0),0,0
#define U_GW1   4608   // 512: [ci][32 rows][4]: W1g row (8 f16)
#define U_GB1q  5120   // 512: [ci][32 rows][4]: (b1g,0),0,0,0
#define U_W2Y   5632   // 2048: [ci][row][16] pairs
#define U_W2G   7680   // 2048
#define F_YB2   9728   // 128 f32
#define F_GB2   9856   // 128 f32
#define U_YW3   9984   // 64: pairs [ci][16]
#define U_GW3   10048  // 64
#define F_YB3   10112  // 4
#define F_GB3   10116  // 4
#define U_CB1   10120  // 8: {pk(1,0),0,0,0} + 4 zeros (zero-frag source)
#define F_RED   10128  // 64: [wave(8)][ci][N,D]
#define F_MODE  10192  // 2
#define U_TOTAL 10194  // 40776 B -> rounds to 40960 -> EXACTLY 4 blocks/CU

// One block per (bn, s1); NT=512 = 8 waves; wave handles 4 position-tiles of
// 16 (pos = wave*64 + t*16 + col).
//
// ROUND 6: streaming body.  R4+R5 proved the register wall: the resident-
// fragment body needs ~128 unified regs -> pinned at 4 waves/SIMD, and both
// more waves (R4) and 2x ILP (R5) spill.  This version keeps only addresses,
// accumulators, a zero-frag, and the ballot'd mask resident (~25 regs) and
// re-reads every A/C fragment from LDS per iteration through VOLATILE loads
// (blocking the hoist).  Budget 64 unified -> 8 waves/SIMD -> 2x latency
// hiding.  LDS traffic (+12 b128/iter) runs on the LDS pipe, parallel to the
// VALU/trans-bound critical path (~40 us floor).
// FALLBACK if counters show spill (WRITE_SIZE in MBs): __launch_bounds__(512,6).
//
// sigma row-permutation (verified R3): sigma(4q+r) = 8q+r / 8q+4+r puts each
// MFMA's C output directly in the next layer's B-fragment layout; zero
// cross-lane fixups.  Quads 1-3 tail garbage never leaks (xor(1,2,4,8)
// reduce stays in each 16-lane group; lane 0 writes).
// NOTE: MFMA calls guarded by __HIP_DEVICE_COMPILE__ (host parse pass).
__global__ __launch_bounds__(NT, 8) void emha_mfma(
    const void* __restrict__ g_pw, const void* __restrict__ g_coset,
    const void* __restrict__ g_mask,
    const void* yW1, const void* yb1, const void* yW2, const void* yb2,
    const void* yW3, const void* yb3,
    const void* gW1, const void* gb1, const void* gW2, const void* gb2,
    const void* gW3, const void* gb3,
    const void* wout, void* outp)
{
    __shared__ __align__(16) unsigned int smu[U_TOTAL];
    float* smf = (float*)smu;
    int*   smi = (int*)smu;
    const int tid = threadIdx.x;

    detect_inline(g_mask, g_coset, tid, smi, F_MODE);
    __syncthreads();
    const int fmode = smi[F_MODE];
    const int mmode = smi[F_MODE + 1];
    __syncthreads();

    const int bn = blockIdx.x >> 2;   // b*128 + n1
    const int s1 = blockIdx.x & 3;
    const int b  = bn >> 7;
    const int n1 = bn & 127;

    // ---- stage pairwise_g slice (pos = n2*4+s2), packed f16 ----
    {
        const int pos = tid;          // NT == 512 == position count
        const int n2 = pos >> 2, s2 = pos & 3;
        float g8[8];
        load8(g_pw, (((bn * NN + n2) * SS + s1) * SS + s2) * DGG, fmode, g8);
#pragma unroll
        for (int q = 0; q < 4; ++q)
            smu[UG_G + pos * 4 + q] = pk2u(g8[2 * q], g8[2 * q + 1]);
    }
    // ---- coset b-slice (f32) ----
    for (int x = tid; x < 2048; x += NT)
        smf[F_FA + x] = loadS(g_coset, b * 2048 + x, fmode);
    // ---- L1 tables with bias columns ----
    for (int x = tid; x < 128; x += NT) {
        smu[U_YW1n + x * 4 + 0] = pk2u(loadS(yW1, 2 * x, fmode), loadS(yW1, 2 * x + 1, fmode));
        smu[U_YW1n + x * 4 + 1] = pk2u(loadS(yb1, x, fmode), 0.f);
        smu[U_YW1n + x * 4 + 2] = 0u;
        smu[U_YW1n + x * 4 + 3] = 0u;
        smu[U_GB1q + x * 4 + 0] = pk2u(loadS(gb1, x, fmode), 0.f);
        smu[U_GB1q + x * 4 + 1] = 0u;
        smu[U_GB1q + x * 4 + 2] = 0u;
        smu[U_GB1q + x * 4 + 3] = 0u;
    }
    stage_pk(&smu[U_GW1], gW1, 512,  fmode, tid);
    stage_pk(&smu[U_W2Y], yW2, 2048, fmode, tid);
    stage_pk(&smu[U_W2G], gW2, 2048, fmode, tid);
    stage_pk(&smu[U_YW3], yW3, 64,   fmode, tid);
    stage_pk(&smu[U_GW3], gW3, 64,   fmode, tid);
    copy_arr(smf, yb2, F_YB2, 128, fmode, tid);
    copy_arr(smf, gb2, F_GB2, 128, fmode, tid);
    copy_arr(smf, yb3, F_YB3, 4, fmode, tid);
    copy_arr(smf, gb3, F_GB3, 4, fmode, tid);
    if (tid < 8) smu[U_CB1 + tid] = (tid == 0) ? 0x00003C00u : 0u;  // pk(1,0), zeros
    __syncthreads();

    const int lane = tid & 63;
    const int wave = tid >> 6;        // 0..7
    const int quad = lane >> 4;
    const int col  = lane & 15;
    const int qpos = n1 * 4 + s1;                    // query index in b-slice
    const int h0   = ((col >> 2) << 3) + (col & 3);  // sigma row for this lane

    // per-wave key-mask bits: lane i holds mask(pos = wave*64+i); ballot
    // gives all 64 bits in 2 resident regs (no LDS mask array)
    const int mymask = load_mask(g_mask, b * 512 + wave * 64 + lane, mmode);
    const unsigned long long km64 = __ballot(mymask != 0);

    const unsigned* Zp = &smu[U_CB1 + 4];   // 16B of zeros
    const f32x4 zf = {0.f, 0.f, 0.f, 0.f};

#pragma unroll 1
    for (int ci = 0; ci < CIN; ++ci) {
        const int rowy = (ci * 32 + h0) * 4;
        // A pointers (quad/col-selected; invalid quads -> zero region).
        // Separate pointers per fragment: imm offsets off a zero base would
        // escape the zero region.
        const unsigned* pAY1a = (quad == 0) ? &smu[U_YW1n + rowy] : Zp;
        const unsigned* pAY1b = (quad == 0) ? &smu[U_YW1n + rowy + 16] : Zp;
        const unsigned* pGA = (quad == 0) ? &smu[U_GW1 + rowy]
                            : ((quad == 1) ? &smu[U_GB1q + rowy] : Zp);
        const unsigned* pGB = (quad == 0) ? &smu[U_GW1 + rowy + 16]
                            : ((quad == 1) ? &smu[U_GB1q + rowy + 16] : Zp);
        const unsigned* pW2 = &smu[U_W2Y + ci * 512 + h0 * 16 + quad * 4];
        const float*    pCb = &smf[F_YB2 + ci * 32 + quad * 8];
        const unsigned* pA3y = (col == 0) ? &smu[U_YW3 + ci * 16 + quad * 4] : Zp;
        const unsigned* pA3g = (col == 0) ? &smu[U_GW3 + ci * 16 + quad * 4] : Zp;
        // B pointer for kg-L1: quad0 walks the g slice; quad1 reads the
        // constant {1,0,...} (bias column k8); quads 2-3 read zeros.
        const unsigned* pBg = (quad == 0) ? &smu[UG_G + (wave * 64 + col) * 4]
                            : ((quad == 1) ? &smu[U_CB1] : Zp);
        const int stepBg = (quad == 0) ? 64 : 0;
        const float* pFA = &smf[F_FA + (wave * 64 + col) * 4 + ci];

        const float fb  = smf[F_FA + qpos * 4 + ci];
        const float b3y = smf[F_YB3 + ci];
        const float b3g = smf[F_GB3 + ci];

        float aN = 0.f, aD = 0.f;
        int amt = col;
#pragma unroll 1
        for (int t = 0; t < 4; ++t) {
            const uvec4 gq = vldu(pBg);
            const float fap = *(volatile const float*)pFA;
            const f16x8 Bg1 = mk_fragv(gq);
            const f16x8 B1y = mk_frag(pk2u(fap, fb), 0x00003C00u, 0u, 0u);

            f32x4 d1a, d1b, dga, dgb;
            {
                const f16x8 AY1a = mk_fragv(vldu(pAY1a));
                const f16x8 AY1b = mk_fragv(vldu(pAY1b));
                const f16x8 GA   = mk_fragv(vldu(pGA));
                const f16x8 GB   = mk_fragv(vldu(pGB));
#if defined(__HIP_DEVICE_COMPILE__)
                d1a = __builtin_amdgcn_mfma_f32_16x16x32_f16(AY1a, B1y, zf, 0, 0, 0);
                d1b = __builtin_amdgcn_mfma_f32_16x16x32_f16(AY1b, B1y, zf, 0, 0, 0);
                dga = __builtin_amdgcn_mfma_f32_16x16x32_f16(GA,   Bg1, zf, 0, 0, 0);
                dgb = __builtin_amdgcn_mfma_f32_16x16x32_f16(GB,   Bg1, zf, 0, 0, 0);
#else
                d1a = zf; d1b = zf; dga = zf; dgb = zf;  // host parse only
#endif
            }
            const f16x8 By = silu_frag(d1a, d1b);
            const f16x8 Bg = silu_frag(dga, dgb);

            f32x4 dy0, dy1, dg0, dg1;
            {
#if defined(__HIP_DEVICE_COMPILE__)
                dy0 = __builtin_amdgcn_mfma_f32_16x16x32_f16(mk_fragv(vldu(pW2)),        By, vldf(pCb),       0, 0, 0);
                dy1 = __builtin_amdgcn_mfma_f32_16x16x32_f16(mk_fragv(vldu(pW2 + 64)),   By, vldf(pCb + 4),   0, 0, 0);
                dg0 = __builtin_amdgcn_mfma_f32_16x16x32_f16(mk_fragv(vldu(pW2 + 2048)), Bg, vldf(pCb + 128), 0, 0, 0);
                dg1 = __builtin_amdgcn_mfma_f32_16x16x32_f16(mk_fragv(vldu(pW2 + 2112)), Bg, vldf(pCb + 132), 0, 0, 0);
#else
                dy0 = zf; dy1 = zf; dg0 = zf; dg1 = zf;  // host parse only
#endif
            }
            const f16x8 By2 = silu_frag(dy0, dy1);
            const f16x8 Bg2 = silu_frag(dg0, dg1);

            f32x4 dy3, dg3;
#if defined(__HIP_DEVICE_COMPILE__)
            dy3 = __builtin_amdgcn_mfma_f32_16x16x32_f16(mk_fragv(vldu(pA3y)), By2, zf, 0, 0, 0);
            dg3 = __builtin_amdgcn_mfma_f32_16x16x32_f16(mk_fragv(vldu(pA3g)), Bg2, zf, 0, 0, 0);
#else
            dy3 = zf; dg3 = zf;  // host parse only
#endif
            // quad-0 lanes hold the L3 dot in reg 0; b3 added in f32 here
            const float kyv = silu_f(dy3[0] + b3y);
            const float kgv = silu_f(dg3[0] + b3g);
            const int   kb  = (int)((km64 >> amt) & 1ull);
            const float e = kb ? exp_f(kyv + kgv) : 0.f;
            aD += e;
            aN += e * fap;

            amt += 16;
            pBg += stepBg;
            pFA += 64;
        }
        // reduce over the 16 positions (col bits, inside each 16-lane group)
        aN += __shfl_xor(aN, 1);  aD += __shfl_xor(aD, 1);
        aN += __shfl_xor(aN, 2);  aD += __shfl_xor(aD, 2);
        aN += __shfl_xor(aN, 4);  aD += __shfl_xor(aD, 4);
        aN += __shfl_xor(aN, 8);  aD += __shfl_xor(aD, 8);
        if (lane == 0) {
            smf[F_RED + (wave * 4 + ci) * 2 + 0] = aN;
            smf[F_RED + (wave * 4 + ci) * 2 + 1] = aD;
        }
    }
    __syncthreads();

    if (tid < COUT) {
        const int o = tid;
        const int m1 = load_mask(g_mask, b * 512 + qpos, mmode);
        float acc = 0.f;
#pragma unroll
        for (int ci = 0; ci < CIN; ++ci) {
            float N = 0.f, D = 0.f;
#pragma unroll
            for (int w = 0; w < 8; ++w) {
                N += smf[F_RED + (w * 4 + ci) * 2 + 0];
                D += smf[F_RED + (w * 4 + ci) * 2 + 1];
            }
            const float fbv = smf[F_FA + qpos * 4 + ci];
            const float cf = m1 ? (fbv + N / D) : 0.f;
            acc += cf * loadS(wout, o * CIN + ci, fmode);
        }
        const int oidx = (bn * SS + s1) * COUT + o;
        if (fmode) ((__hip_bfloat16*)outp)[oidx] = __float2bfloat16(acc);
        else       ((float*)outp)[oidx] = acc;
    }
}

extern "C" void kernel_launch(void* const* d_in, const int* in_sizes, int n_in,
                              void* d_out, int out_size, void* d_ws, size_t ws_size,
                              hipStream_t stream) {
    emha_mfma<<<BB * NN * SS, NT, 0, stream>>>(
        d_in[0], d_in[1], d_in[2],
        d_in[3], d_in[4], d_in[5], d_in[6], d_in[7], d_in[8],
        d_in[9], d_in[10], d_in[11], d_in[12], d_in[13], d_in[14],
        d_in[15], d_out);
}

// Round 7
// 168.904 us; speedup vs baseline: 1.1704x; 1.1704x over previous
//
#include <hip/hip_runtime.h>
#include <hip/hip_bf16.h>

#define BB   2
#define NN   128
#define SS   4
#define DGG  8
#define CIN  4
#define COUT 8
#define HH   32
#define NT   256   // 4 waves/block, (256,4): the ONLY config that doesn't spill (R4/R5/R6)

typedef __attribute__((ext_vector_type(4))) float          fvec4;
typedef __attribute__((ext_vector_type(4))) unsigned short usvec4;
typedef __attribute__((ext_vector_type(8))) unsigned short usvec8;
typedef __attribute__((ext_vector_type(2))) __fp16         half2v;
typedef __attribute__((ext_vector_type(8))) __fp16         f16x8;
typedef __attribute__((ext_vector_type(4))) float          f32x4;
typedef __attribute__((ext_vector_type(4))) unsigned int   uvec4;

__device__ __forceinline__ float bf2f(unsigned short u) {
    return __uint_as_float(((unsigned int)u) << 16);
}
__device__ __forceinline__ float silu_f(float x) {
    float e = __builtin_amdgcn_exp2f(x * -1.44269504f);
    return x * __builtin_amdgcn_rcpf(1.0f + e);
}
__device__ __forceinline__ float exp_f(float x) {
    return __builtin_amdgcn_exp2f(x * 1.44269504f);
}

__device__ __forceinline__ unsigned int pk2u(float a, float b) {
#if __has_builtin(__builtin_amdgcn_cvt_pkrtz)
    half2v h = __builtin_amdgcn_cvt_pkrtz(a, b);
#else
    half2v h; h[0] = (__fp16)a; h[1] = (__fp16)b;
#endif
    union { half2v h; unsigned int u; } x; x.h = h; return x.u;
}
union FU { uvec4 u; f16x8 h; };
__device__ __forceinline__ f16x8 mk_frag(unsigned a, unsigned b, unsigned c, unsigned d) {
    FU x; x.u = (uvec4){a, b, c, d}; return x.h;
}
__device__ __forceinline__ f16x8 mk_fragv(uvec4 u) {
    FU x; x.u = u; return x.h;
}
// silu + pack two f32x4 MFMA outputs into one B-fragment (j = 0..7)
__device__ __forceinline__ f16x8 silu_frag(f32x4 a, f32x4 b) {
    return mk_frag(pk2u(silu_f(a[0]), silu_f(a[1])),
                   pk2u(silu_f(a[2]), silu_f(a[3])),
                   pk2u(silu_f(b[0]), silu_f(b[1])),
                   pk2u(silu_f(b[2]), silu_f(b[3])));
}

__device__ __forceinline__ float loadS(const void* p, int idx, int fmode) {
    return fmode ? bf2f(((const unsigned short*)p)[idx])
                 : ((const float*)p)[idx];
}
__device__ __forceinline__ void load8(const void* p, int base, int fmode, float* dst) {
    if (fmode) {
        usvec8 v = *(const usvec8*)((const unsigned short*)p + base);
#pragma unroll
        for (int d = 0; d < 8; ++d) dst[d] = bf2f(v[d]);
    } else {
        fvec4 a = *(const fvec4*)((const float*)p + base);
        fvec4 b = *(const fvec4*)((const float*)p + base + 4);
        dst[0] = a[0]; dst[1] = a[1]; dst[2] = a[2]; dst[3] = a[3];
        dst[4] = b[0]; dst[5] = b[1]; dst[6] = b[2]; dst[7] = b[3];
    }
}
__device__ __forceinline__ int load_mask(const void* p, int idx, int mmode) {
    if (mmode == 0) return ((const int*)p)[idx] != 0;
    if (mmode == 1) return ((const unsigned short*)p)[idx] != 0;
    if (mmode == 2) return ((const unsigned char*)p)[idx] != 0;
    return ((const unsigned int*)p)[idx] != 0;
}
__device__ __forceinline__ void stage_pk(unsigned int* dst, const void* src,
                                         int pairs, int fmode, int tid) {
    if (fmode) {
        const unsigned short* s = (const unsigned short*)src;
        for (int x = tid; x < pairs; x += NT)
            dst[x] = pk2u(bf2f(s[2 * x]), bf2f(s[2 * x + 1]));
    } else {
        const float* s = (const float*)src;
        for (int x = tid; x < pairs; x += NT)
            dst[x] = pk2u(s[2 * x], s[2 * x + 1]);
    }
}
__device__ __forceinline__ void copy_arr(float* sm, const void* src, int off,
                                         int cnt, int fmode, int tid) {
    if (fmode) {
        const unsigned short* s = (const unsigned short*)src;
        for (int x = tid; x < cnt; x += NT) sm[off + x] = bf2f(s[x]);
    } else {
        const float* s = (const float*)src;
        for (int x = tid; x < cnt; x += NT) sm[off + x] = s[x];
    }
}
// modes: [0]=float dtype (0=f32,1=bf16), [1]=mask dtype (0=i32,1=bf16,2=u8,3=f32)
__device__ __forceinline__ void detect_inline(const void* g_mask, const void* g_coset,
                                              int tid, int* smi, int slot) {
    if (tid < 64) {
        const unsigned short* cu = (const unsigned short*)g_coset;
        unsigned short v = cu[2 * tid];
        int e = (v >> 7) & 0xFF;
        int hits = __popcll(__ballot(e >= 110 && e <= 135));
        int fmode_ = (hits > 32) ? 1 : 0;
        const unsigned short* mu = (const unsigned short*)g_mask;
        int evenBF = 0, any3 = 0, anyByte = 0;
        for (int r = 0; r < 8; ++r) {
            int idx = tid + r * 64;
            unsigned short m = mu[idx];
            if (m == 0x3F80) { any3 = 1; if (!(idx & 1)) evenBF = 1; }
            if (m == 0x0101 || m == 0x0100) anyByte = 1;
        }
        evenBF  = (__ballot(evenBF)  != 0ull);
        any3    = (__ballot(any3)    != 0ull);
        anyByte = (__ballot(anyByte) != 0ull);
        if (tid == 0) {
            smi[slot]     = fmode_;
            smi[slot + 1] = evenBF ? 1 : (any3 ? 3 : (anyByte ? 2 : 0));
        }
    }
}

// LDS layout (u32 units).  vs R3: L1 bias columns folded INTO the A-row
// tables (U_YW1n rows = (w0,w1),(b1y,0),0,0; U_GB1q = quad-1 bias rows),
// mask moved to ballot'd SGPRs, b3 applied post-MFMA -> frees 24 resident
// C-operand VGPRs for unroll-2 scheduling headroom.
#define UG_G    0      // 2048: pairwise_g slice, packed f16 [pos][4]
#define F_FA    2048   // 2048 f32: coset b-slice [pos][ci]
#define U_YW1n  4096   // 512: [ci][32 rows][4]: (w0,w1),(b1y,0),0,0
#define U_GW1   4608   // 512: [ci][32 rows][4]: W1g row (8 f16)
#define U_GB1q  5120   // 512: [ci][32 rows][4]: (b1g,0),0,0,0   (k=8 bias col)
#define U_W2Y   5632   // 2048: pairs [ci][row][16]
#define U_W2G   7680   // 2048
#define F_YB2   9728   // 128 f32
#define F_GB2   9856   // 128 f32
#define U_YW3   9984   // 64: pairs [ci][16]
#define U_GW3   10048  // 64
#define F_YB3   10112  // 4
#define F_GB3   10116  // 4
#define U_CB1   10120  // 8: {pk(1,0),0,0,0} + 4 zeros (Zp zero-frag region)
#define F_RED   10128  // 32: [wave(4)][ci][N,D]
#define F_MODE  10160  // 2
#define U_TOTAL 10162  // 40648 B -> still 4 blocks/CU (4*40.96KB = 160KB cap)

// One block per (bn, s1); 256 threads = 4 waves; wave handles 8 position-
// tiles of 16 (pos = wave*128 + t*16 + col).
//
// ROUND 7: register-ledger fix at the PROVEN (256,4) config.  R4/R5/R6
// proved >4 waves/SIMD always spills (64-unified budget < transients alone).
// R3's body = ~76 resident + ~45 transient = ~121/128 -> no scheduler
// headroom, and `unroll 1` meant every iteration began with a cold ~120cyc
// LDS-read stall (scheduler can't cross the backedge).  This round:
//   (a) fold b1y into A at k=2 (B word1 = const f16 1.0), b1g at k=8 via
//       quad-1 A rows (U_GB1q) + quad-1 B = {1,0,..} const region, L3 C = zf
//       with b3 post-added in f32 — all three mechanisms ran correctly in
//       R6's passing run; frees 24 resident VGPRs.
//   (b) mask via two __ballot SGPR pairs (SGPRs don't count vs VGPR budget).
//   (c) #pragma unroll 2 SEQUENTIAL (not R5's parallel phasing): lets the
//       pressure-aware scheduler hoist iter t+1's gq/fap loads (~5 regs)
//       over iter t's L2/L3 tail.
// FALLBACK if spill signature (WRITE_SIZE in MBs): revert (c) only.
//
// sigma row-permutation (verified R3): sigma(4q+r) = 8q+r / 8q+4+r puts each
// MFMA's C output directly in the next layer's B-fragment layout; zero
// cross-lane fixups.  Quads 1-3 tail garbage never leaks (xor(1,2,4,8)
// reduce stays in each 16-lane group; lane 0 writes).
// NOTE: MFMA calls guarded by __HIP_DEVICE_COMPILE__ (host parse pass).
__global__ __launch_bounds__(NT, 4) void emha_mfma(
    const void* __restrict__ g_pw, const void* __restrict__ g_coset,
    const void* __restrict__ g_mask,
    const void* yW1, const void* yb1, const void* yW2, const void* yb2,
    const void* yW3, const void* yb3,
    const void* gW1, const void* gb1, const void* gW2, const void* gb2,
    const void* gW3, const void* gb3,
    const void* wout, void* outp)
{
    __shared__ __align__(16) unsigned int smu[U_TOTAL];
    float* smf = (float*)smu;
    int*   smi = (int*)smu;
    const int tid = threadIdx.x;

    detect_inline(g_mask, g_coset, tid, smi, F_MODE);
    __syncthreads();
    const int fmode = smi[F_MODE];
    const int mmode = smi[F_MODE + 1];
    __syncthreads();

    const int bn = blockIdx.x >> 2;   // b*128 + n1
    const int s1 = blockIdx.x & 3;
    const int b  = bn >> 7;
    const int n1 = bn & 127;

    // ---- stage pairwise_g slice (pos = n2*4+s2), packed f16 ----
#pragma unroll
    for (int it = 0; it < 2; ++it) {
        const int pos = tid + it * 256;
        const int n2 = pos >> 2, s2 = pos & 3;
        float g8[8];
        load8(g_pw, (((bn * NN + n2) * SS + s1) * SS + s2) * DGG, fmode, g8);
#pragma unroll
        for (int q = 0; q < 4; ++q)
            smu[UG_G + pos * 4 + q] = pk2u(g8[2 * q], g8[2 * q + 1]);
    }
    // ---- coset b-slice (f32) ----
    for (int x = tid; x < 2048; x += NT)
        smf[F_FA + x] = loadS(g_coset, b * 2048 + x, fmode);
    // ---- L1 tables with folded bias columns ----
    for (int x = tid; x < 128; x += NT) {
        smu[U_YW1n + x * 4 + 0] = pk2u(loadS(yW1, 2 * x, fmode), loadS(yW1, 2 * x + 1, fmode));
        smu[U_YW1n + x * 4 + 1] = pk2u(loadS(yb1, x, fmode), 0.f);
        smu[U_YW1n + x * 4 + 2] = 0u;
        smu[U_YW1n + x * 4 + 3] = 0u;
        smu[U_GB1q + x * 4 + 0] = pk2u(loadS(gb1, x, fmode), 0.f);
        smu[U_GB1q + x * 4 + 1] = 0u;
        smu[U_GB1q + x * 4 + 2] = 0u;
        smu[U_GB1q + x * 4 + 3] = 0u;
    }
    stage_pk(&smu[U_GW1], gW1, 512,  fmode, tid);
    stage_pk(&smu[U_W2Y], yW2, 2048, fmode, tid);
    stage_pk(&smu[U_W2G], gW2, 2048, fmode, tid);
    stage_pk(&smu[U_YW3], yW3, 64,   fmode, tid);
    stage_pk(&smu[U_GW3], gW3, 64,   fmode, tid);
    copy_arr(smf, yb2, F_YB2, 128, fmode, tid);
    copy_arr(smf, gb2, F_GB2, 128, fmode, tid);
    copy_arr(smf, yb3, F_YB3, 4, fmode, tid);
    copy_arr(smf, gb3, F_GB3, 4, fmode, tid);
    if (tid < 8) smu[U_CB1 + tid] = (tid == 0) ? 0x00003C00u : 0u;  // pk(1,0), zeros

    // ---- key-mask bits -> 2x 64-bit SGPR sets per wave (no LDS, no VGPRs)
    const int lane = tid & 63;
    const int wave = tid >> 6;        // 0..3; wave covers pos wave*128..+127
    const int mLo = load_mask(g_mask, b * 512 + wave * 128 + lane, mmode);
    const int mHi = load_mask(g_mask, b * 512 + wave * 128 + 64 + lane, mmode);
    const unsigned long long kmL = __ballot(mLo != 0);
    const unsigned long long kmH = __ballot(mHi != 0);
    __syncthreads();

    const int quad = lane >> 4;
    const int col  = lane & 15;
    const int qpos = n1 * 4 + s1;                    // query index in b-slice
    const int h0   = ((col >> 2) << 3) + (col & 3);  // sigma row for this lane
    const unsigned* Zp = &smu[U_CB1 + 4];            // 16B of zeros
    const f32x4 zf = {0.f, 0.f, 0.f, 0.f};

#pragma unroll 1
    for (int ci = 0; ci < CIN; ++ci) {
        const int rowy = (ci * 32 + h0) * 4;
        // L1 A-frags (bias folded; quads select their k-range source)
        const f16x8 AY1a = mk_fragv(*(const uvec4*)((quad == 0) ? &smu[U_YW1n + rowy] : Zp));
        const f16x8 AY1b = mk_fragv(*(const uvec4*)((quad == 0) ? &smu[U_YW1n + rowy + 16] : Zp));
        const f16x8 GA = mk_fragv(*(const uvec4*)((quad == 0) ? &smu[U_GW1 + rowy]
                                   : (quad == 1) ? &smu[U_GB1q + rowy] : Zp));
        const f16x8 GB = mk_fragv(*(const uvec4*)((quad == 0) ? &smu[U_GW1 + rowy + 16]
                                   : (quad == 1) ? &smu[U_GB1q + rowy + 16] : Zp));
        // L2 A-frags (full K=32) + b2 C-operands (kept resident)
        const f16x8 Ay0 = mk_fragv(*(const uvec4*)&smu[U_W2Y + ci * 512 + h0 * 16 + quad * 4]);
        const f16x8 Ay1 = mk_fragv(*(const uvec4*)&smu[U_W2Y + ci * 512 + (h0 + 4) * 16 + quad * 4]);
        const f16x8 Ag0 = mk_fragv(*(const uvec4*)&smu[U_W2G + ci * 512 + h0 * 16 + quad * 4]);
        const f16x8 Ag1 = mk_fragv(*(const uvec4*)&smu[U_W2G + ci * 512 + (h0 + 4) * 16 + quad * 4]);
        const fvec4 cY0 = *(const fvec4*)&smf[F_YB2 + ci * 32 + quad * 8];
        const fvec4 cY1 = *(const fvec4*)&smf[F_YB2 + ci * 32 + quad * 8 + 4];
        const fvec4 cG0 = *(const fvec4*)&smf[F_GB2 + ci * 32 + quad * 8];
        const fvec4 cG1 = *(const fvec4*)&smf[F_GB2 + ci * 32 + quad * 8 + 4];
        // L3 A-frags (row 0 = w3 on col==0 lanes); C = zf, b3 post-added
        const f16x8 A3y = mk_fragv(*(const uvec4*)((col == 0) ? &smu[U_YW3 + ci * 16 + quad * 4] : Zp));
        const f16x8 A3g = mk_fragv(*(const uvec4*)((col == 0) ? &smu[U_GW3 + ci * 16 + quad * 4] : Zp));

        const float fb  = smf[F_FA + qpos * 4 + ci];
        const float b3y = smf[F_YB3 + ci];
        const float b3g = smf[F_GB3 + ci];

        // per-iter B sources: quad0 walks g; quad1 reads {1,0..} (bias col);
        // quads 2-3 read zeros (their A rows are zero anyway)
        const unsigned* pBg = (quad == 0) ? &smu[UG_G + (wave * 128 + col) * 4]
                            : ((quad == 1) ? &smu[U_CB1] : Zp);
        const int stepBg = (quad == 0) ? 64 : 0;
        const float* pFA = &smf[F_FA + (wave * 128 + col) * 4 + ci];

        float aN = 0.f, aD = 0.f;
#pragma unroll 2
        for (int t = 0; t < 8; ++t) {
            const uvec4 gq = *(const uvec4*)pBg;
            const float fap = *pFA;
            const f16x8 Bg1 = mk_fragv(gq);
            // B word1 = pk(1,0): k=2 supplies the constant-1 bias column
            const f16x8 B1y = mk_frag(pk2u(fap, fb), 0x00003C00u, 0u, 0u);

            f32x4 d1a, d1b, dga, dgb, dy0, dy1, dg0, dg1, dy3, dg3;
#if defined(__HIP_DEVICE_COMPILE__)
            d1a = __builtin_amdgcn_mfma_f32_16x16x32_f16(AY1a, B1y, zf, 0, 0, 0);
            d1b = __builtin_amdgcn_mfma_f32_16x16x32_f16(AY1b, B1y, zf, 0, 0, 0);
            dga = __builtin_amdgcn_mfma_f32_16x16x32_f16(GA,   Bg1, zf, 0, 0, 0);
            dgb = __builtin_amdgcn_mfma_f32_16x16x32_f16(GB,   Bg1, zf, 0, 0, 0);
#else
            d1a = zf; d1b = zf; dga = zf; dgb = zf;  // host parse only
#endif
            const f16x8 By = silu_frag(d1a, d1b);
            const f16x8 Bg = silu_frag(dga, dgb);

#if defined(__HIP_DEVICE_COMPILE__)
            dy0 = __builtin_amdgcn_mfma_f32_16x16x32_f16(Ay0, By, cY0, 0, 0, 0);
            dy1 = __builtin_amdgcn_mfma_f32_16x16x32_f16(Ay1, By, cY1, 0, 0, 0);
            dg0 = __builtin_amdgcn_mfma_f32_16x16x32_f16(Ag0, Bg, cG0, 0, 0, 0);
            dg1 = __builtin_amdgcn_mfma_f32_16x16x32_f16(Ag1, Bg, cG1, 0, 0, 0);
#else
            dy0 = cY0; dy1 = cY1; dg0 = cG0; dg1 = cG1;  // host parse only
#endif
            const f16x8 By2 = silu_frag(dy0, dy1);
            const f16x8 Bg2 = silu_frag(dg0, dg1);

#if defined(__HIP_DEVICE_COMPILE__)
            dy3 = __builtin_amdgcn_mfma_f32_16x16x32_f16(A3y, By2, zf, 0, 0, 0);
            dg3 = __builtin_amdgcn_mfma_f32_16x16x32_f16(A3g, Bg2, zf, 0, 0, 0);
#else
            dy3 = zf; dg3 = zf;  // host parse only
#endif
            // quad-0 lanes hold the L3 dot in reg 0; b3 added in f32 here.
            // Quads 1-3 compute garbage that never enters the reduce.
            const float kyv = silu_f(dy3[0] + b3y);
            const float kgv = silu_f(dg3[0] + b3g);
            const unsigned long long sel = (t < 4) ? kmL : kmH;  // t uniform
            const int kb = (int)((sel >> (((t & 3) << 4) + col)) & 1);
            const float e = kb ? exp_f(kyv + kgv) : 0.f;
            aD += e;
            aN += e * fap;

            pBg += stepBg;
            pFA += 64;
        }
        // reduce over the 16 positions (col bits, inside each 16-lane group)
        aN += __shfl_xor(aN, 1);  aD += __shfl_xor(aD, 1);
        aN += __shfl_xor(aN, 2);  aD += __shfl_xor(aD, 2);
        aN += __shfl_xor(aN, 4);  aD += __shfl_xor(aD, 4);
        aN += __shfl_xor(aN, 8);  aD += __shfl_xor(aD, 8);
        if (lane == 0) {
            smf[F_RED + (wave * 4 + ci) * 2 + 0] = aN;
            smf[F_RED + (wave * 4 + ci) * 2 + 1] = aD;
        }
    }
    __syncthreads();

    if (tid < COUT) {
        const int o = tid;
        const int m1 = load_mask(g_mask, b * 512 + qpos, mmode);
        float acc = 0.f;
#pragma unroll
        for (int ci = 0; ci < CIN; ++ci) {
            float N = 0.f, D = 0.f;
#pragma unroll
            for (int w = 0; w < 4; ++w) {
                N += smf[F_RED + (w * 4 + ci) * 2 + 0];
                D += smf[F_RED + (w * 4 + ci) * 2 + 1];
            }
            const float fbv = smf[F_FA + qpos * 4 + ci];
            const float cf = m1 ? (fbv + N / D) : 0.f;
            acc += cf * loadS(wout, o * CIN + ci, fmode);
        }
        const int oidx = (bn * SS + s1) * COUT + o;
        if (fmode) ((__hip_bfloat16*)outp)[oidx] = __float2bfloat16(acc);
        else       ((float*)outp)[oidx] = acc;
    }
}

extern "C" void kernel_launch(void* const* d_in, const int* in_sizes, int n_in,
                              void* d_out, int out_size, void* d_ws, size_t ws_size,
                              hipStream_t stream) {
    emha_mfma<<<BB * NN * SS, NT, 0, stream>>>(
        d_in[0], d_in[1], d_in[2],
        d_in[3], d_in[4], d_in[5], d_in[6], d_in[7], d_in[8],
        d_in[9], d_in[10], d_in[11], d_in[12], d_in[13], d_in[14],
        d_in[15], d_out);
}